// Round 7
// baseline (82.122 us; speedup 1.0000x reference)
//
#include <hip/hip_runtime.h>

// Problem: N=65536 rows, H=512, E=8, OUT=2.
//   oh=x[:,0:8], delta=x[:,8], phi=x[:,9]
//   h  = relu(delta*w1 + b1 + phi*(oh@meta_w) + oh@meta_b)   -> one K=32 bf16 MFMA GEMM
//   h2 = relu(h @ w2 + b2)                                   -> main GEMM, bf16 MFMA, K=512
//   out = h2 @ w3 + b3                                       -> fused shuffle-reduce epilogue
//
// R7: R6 structure (16 waves, wave tile 64x32, acc[4][2]=32 AGPR) but WITHOUT
// a min-waves cap: default 1024-thr bound caps at 128 regs total, live set
// ~96 VGPR + 32 AGPR fits with ZERO spill (R5/R6 caps forced 22/45 MB spills).
// 1-deep software prefetch of B-frags (8 regs) hides L2 latency. K-loop
// barrier-free; w2s pre-packed in fragment order, L2-resident.

#define BM 64

typedef float f32x4 __attribute__((ext_vector_type(4)));
typedef short s16x8 __attribute__((ext_vector_type(8)));

__device__ __forceinline__ short f2bf(float f) {
    union { float f; unsigned u; } c; c.f = f;
    unsigned u = c.u;
    return (short)((u + 0x7FFFu + ((u >> 16) & 1u)) >> 16);  // RNE
}

// ---------------- prep: build bf16 weight images in workspace ----------------
// w2s layout: [ks=16][g=4][n=512][j=8] bf16  (B-fragment order)
//   element (ks,g,n,j) = w2[k][n] with k = ks*32 + g*8 + j
// waugS layout: [col=512][k=32] bf16, rows of W' = [meta_w(8); meta_b(8); w1; b1; 0...]
__global__ void prep_kernel(const float* __restrict__ w1, const float* __restrict__ b1,
                            const float* __restrict__ mw, const float* __restrict__ mb,
                            const float* __restrict__ w2,
                            short* __restrict__ w2s, short* __restrict__ waugS) {
    int id = blockIdx.x * 256 + threadIdx.x;
    if (id < 512 * 512) {
        int k = id / 512, n = id % 512;
        int ks = k >> 5, g = (k >> 3) & 3, j = k & 7;
        w2s[(((ks * 4 + g) * 512) + n) * 8 + j] = f2bf(w2[id]);
    }
    if (id < 512 * 32) {
        int col = id >> 5, k = id & 31;
        float v = 0.f;
        if (k < 8)        v = mw[k * 512 + col];
        else if (k < 16)  v = mb[(k - 8) * 512 + col];
        else if (k == 16) v = w1[col];
        else if (k == 17) v = b1[col];
        waugS[col * 32 + k] = f2bf(v);
    }
}

// ---------------- fused MLP ----------------
// grid 1024 blocks x 1024 threads (16 waves). Block tile: 64 rows x 512 cols.
// Wave w owns cols [w*32, w*32+32), all 64 rows -> acc 4(m) x 2(n) frags of 16x16.
__global__ __launch_bounds__(1024) void fused_mlp(
    const float* __restrict__ x, const short* __restrict__ waugS,
    const short* __restrict__ w2s, const float* __restrict__ b2,
    const float* __restrict__ w3, const float* __restrict__ b3,
    float* __restrict__ out) {

    __shared__ __align__(16) short hls[64 * 512];           // 64KB, XOR-swizzled
    __shared__ float xls[64 * 10];                          // 2560 B
    __shared__ float oacc[128];                             // 512 B

    const int tid  = threadIdx.x;
    const int wv   = tid >> 6;           // 0..15
    const int lane = tid & 63;
    const int l15  = lane & 15;
    const int g    = lane >> 4;
    const long rowbase = (long)blockIdx.x * BM;

    // ---- load x tile (64x10 f32 = 640 floats), zero out-acc ----
    if (tid < BM * 10) xls[tid] = x[rowbase * 10 + tid];
    if (tid < 128) oacc[tid] = 0.f;
    __syncthreads();

    // ---- layer 1: one K=32 MFMA pass; h -> LDS (swizzled bf16) ----
    {
        s16x8 afr[4];
#pragma unroll
        for (int m = 0; m < 4; ++m) {
            int r = m * 16 + l15;
            float v[8];
            if (g == 0) {                    // k=0..7 : oh * phi
                float phi = xls[r * 10 + 9];
#pragma unroll
                for (int j = 0; j < 8; ++j) v[j] = xls[r * 10 + j] * phi;
            } else if (g == 1) {             // k=8..15 : oh
#pragma unroll
                for (int j = 0; j < 8; ++j) v[j] = xls[r * 10 + j];
            } else if (g == 2) {             // k=16,17 : delta, 1
                v[0] = xls[r * 10 + 8]; v[1] = 1.f;
#pragma unroll
                for (int j = 2; j < 8; ++j) v[j] = 0.f;
            } else {                         // k=24..31 : 0
#pragma unroll
                for (int j = 0; j < 8; ++j) v[j] = 0.f;
            }
            s16x8 a;
#pragma unroll
            for (int j = 0; j < 8; ++j) a[j] = f2bf(v[j]);
            afr[m] = a;
        }
#pragma unroll
        for (int nf = 0; nf < 2; ++nf) {
            int col = wv * 32 + nf * 16 + l15;
            s16x8 bfr = *(const s16x8*)(waugS + col * 32 + g * 8);
#pragma unroll
            for (int m = 0; m < 4; ++m) {
                f32x4 c = {0.f, 0.f, 0.f, 0.f};
                c = __builtin_amdgcn_mfma_f32_16x16x32_bf16(afr[m], bfr, c, 0, 0, 0);
#pragma unroll
                for (int r4 = 0; r4 < 4; ++r4) {
                    int row = m * 16 + g * 4 + r4;
                    float hv = c[r4];
                    hv = hv > 0.f ? hv : 0.f;
                    int byte = (row * 1024 + col * 2) ^ ((row & 7) << 4);
                    *(short*)((char*)hls + byte) = f2bf(hv);
                }
            }
        }
    }
    __syncthreads();   // h ready; hls is read-only from here -> no more barriers

    // ---- layer 2: K=512 in 16 steps of 32; B-frags from L2, 1-deep prefetch ----
    f32x4 acc[4][2];
#pragma unroll
    for (int m = 0; m < 4; ++m)
#pragma unroll
        for (int n = 0; n < 2; ++n) acc[m][n] = (f32x4){0.f, 0.f, 0.f, 0.f};

    // B-frag address for (t, g, col): w2s + (((t*4+g)*512)+col)*8 shorts
    const s16x8* __restrict__ w2v = (const s16x8*)w2s;
    const int colbase = wv * 32 + l15;

    s16x8 bf[2];
#pragma unroll
    for (int n = 0; n < 2; ++n)
        bf[n] = w2v[(0 * 4 + g) * 512 + colbase + n * 16];

    for (int t = 0; t < 16; ++t) {
        s16x8 bfn[2];
        if (t < 15) {
#pragma unroll
            for (int n = 0; n < 2; ++n)
                bfn[n] = w2v[((t + 1) * 4 + g) * 512 + colbase + n * 16];
        }
        s16x8 af[4];
#pragma unroll
        for (int m = 0; m < 4; ++m) {
            int row = m * 16 + l15;
            int byte = (row * 1024 + (t * 32 + g * 8) * 2) ^ ((row & 7) << 4);
            af[m] = *(const s16x8*)((const char*)hls + byte);
        }
#pragma unroll
        for (int m = 0; m < 4; ++m)
#pragma unroll
            for (int n = 0; n < 2; ++n)
                acc[m][n] = __builtin_amdgcn_mfma_f32_16x16x32_bf16(af[m], bf[n], acc[m][n], 0, 0, 0);
#pragma unroll
        for (int n = 0; n < 2; ++n) bf[n] = bfn[n];
    }

    // ---- layer 3: relu(acc+b2) @ w3, fused reduce ----
    float p[4][4][2];
#pragma unroll
    for (int m = 0; m < 4; ++m)
#pragma unroll
        for (int r4 = 0; r4 < 4; ++r4) { p[m][r4][0] = 0.f; p[m][r4][1] = 0.f; }

#pragma unroll
    for (int n = 0; n < 2; ++n) {
        int col = wv * 32 + n * 16 + l15;
        float bb2 = b2[col];
        float w30 = w3[col * 2 + 0];
        float w31 = w3[col * 2 + 1];
#pragma unroll
        for (int m = 0; m < 4; ++m)
#pragma unroll
            for (int r4 = 0; r4 < 4; ++r4) {
                float v = acc[m][n][r4] + bb2;
                v = v > 0.f ? v : 0.f;
                p[m][r4][0] += v * w30;
                p[m][r4][1] += v * w31;
            }
    }
    // butterfly-reduce over the 16 lanes sharing the same rows (same g)
#pragma unroll
    for (int m = 0; m < 4; ++m)
#pragma unroll
        for (int r4 = 0; r4 < 4; ++r4)
#pragma unroll
            for (int o = 0; o < 2; ++o) {
                float v = p[m][r4][o];
                v += __shfl_xor(v, 1);
                v += __shfl_xor(v, 2);
                v += __shfl_xor(v, 4);
                v += __shfl_xor(v, 8);
                if (l15 == 0) atomicAdd(&oacc[(m * 16 + g * 4 + r4) * 2 + o], v);
            }
    __syncthreads();

    if (tid < 128) {
        int row = tid >> 1, o = tid & 1;
        out[(rowbase + row) * 2 + o] = oacc[tid] + b3[o];
    }
}

extern "C" void kernel_launch(void* const* d_in, const int* in_sizes, int n_in,
                              void* d_out, int out_size, void* d_ws, size_t ws_size,
                              hipStream_t stream) {
    const float* x  = (const float*)d_in[0];
    const float* w1 = (const float*)d_in[1];
    const float* b1 = (const float*)d_in[2];
    const float* mw = (const float*)d_in[3];
    const float* mb = (const float*)d_in[4];
    const float* w2 = (const float*)d_in[5];
    const float* b2 = (const float*)d_in[6];
    const float* w3 = (const float*)d_in[7];
    const float* b3 = (const float*)d_in[8];
    float* out = (float*)d_out;

    short* w2s   = (short*)d_ws;          // 512 KB
    short* waugS = w2s + 512 * 512;       // 32 KB

    prep_kernel<<<1024, 256, 0, stream>>>(w1, b1, mw, mb, w2, w2s, waugS);
    fused_mlp<<<65536 / BM, 1024, 0, stream>>>(x, waugS, w2s, b2, w3, b3, out);
}

// Round 8
// 70.926 us; speedup vs baseline: 1.1578x; 1.1578x over previous
//
#include <hip/hip_runtime.h>

// Problem: N=65536 rows, H=512, E=8, OUT=2.
//   oh=x[:,0:8], delta=x[:,8], phi=x[:,9]
//   h  = relu(delta*w1 + b1 + phi*(oh@meta_w) + oh@meta_b)   -> one K=32 bf16 MFMA GEMM
//   h2 = relu(h @ w2 + b2)                                   -> main GEMM, bf16 MFMA, K=512
//   out = h2 @ w3 + b3                                       -> fused shuffle-reduce epilogue
//
// R8: back to 8 waves x (64 rows x 64 cols) wave tile = acc[4][4] (16 MFMA per
// fetch round), uncapped regs. K-loop de-VALU'd:
//   - h kept in LDS in FRAGMENT order [k>>3][row][k&7] -> af ds_read_b128 uses
//     one base VGPR + immediate offsets (t*4096+m*256), zero addr VALU,
//     conflict-free (quarter-wave reads 256B contiguous).
//   - bf ping-pong regs (bfA/bfB), 2x-unrolled loop -> no per-iter reg copies.
//   - B-frags straight from L2 (w2s pre-packed fragment-order), no barriers.

#define BM 64

typedef float f32x4 __attribute__((ext_vector_type(4)));
typedef short s16x8 __attribute__((ext_vector_type(8)));

__device__ __forceinline__ short f2bf(float f) {
    union { float f; unsigned u; } c; c.f = f;
    unsigned u = c.u;
    return (short)((u + 0x7FFFu + ((u >> 16) & 1u)) >> 16);  // RNE
}

// ---------------- prep: build bf16 weight images in workspace ----------------
// w2s layout: [ks=16][g=4][n=512][j=8] bf16  (B-fragment order)
//   element (ks,g,n,j) = w2[k][n] with k = ks*32 + g*8 + j
// waugS layout: [col=512][k=32] bf16, rows of W' = [meta_w(8); meta_b(8); w1; b1; 0...]
__global__ void prep_kernel(const float* __restrict__ w1, const float* __restrict__ b1,
                            const float* __restrict__ mw, const float* __restrict__ mb,
                            const float* __restrict__ w2,
                            short* __restrict__ w2s, short* __restrict__ waugS) {
    int id = blockIdx.x * 256 + threadIdx.x;
    if (id < 512 * 512) {
        int k = id / 512, n = id % 512;
        int ks = k >> 5, g = (k >> 3) & 3, j = k & 7;
        w2s[(((ks * 4 + g) * 512) + n) * 8 + j] = f2bf(w2[id]);
    }
    if (id < 512 * 32) {
        int col = id >> 5, k = id & 31;
        float v = 0.f;
        if (k < 8)        v = mw[k * 512 + col];
        else if (k < 16)  v = mb[(k - 8) * 512 + col];
        else if (k == 16) v = w1[col];
        else if (k == 17) v = b1[col];
        waugS[col * 32 + k] = f2bf(v);
    }
}

// ---------------- fused MLP ----------------
// grid 1024 blocks x 512 threads (8 waves). Block tile: 64 rows x 512 cols.
// Wave w owns cols [w*64, w*64+64), all 64 rows -> acc 4(m) x 4(n) frags.
__global__ __launch_bounds__(512) void fused_mlp(
    const float* __restrict__ x, const short* __restrict__ waugS,
    const short* __restrict__ w2s, const float* __restrict__ b2,
    const float* __restrict__ w3, const float* __restrict__ b3,
    float* __restrict__ out) {

    // h in FRAGMENT order: short idx = (k>>3)*512 + row*8 + (k&7)
    __shared__ __align__(16) short haug[64 * 512];          // 64KB
    __shared__ float xls[64 * 10];                          // 2560 B
    __shared__ float oacc[128];                             // 512 B

    const int tid  = threadIdx.x;
    const int wv   = tid >> 6;           // 0..7
    const int lane = tid & 63;
    const int l15  = lane & 15;
    const int g    = lane >> 4;
    const long rowbase = (long)blockIdx.x * BM;

    // ---- load x tile (64x10 f32 = 640 floats, strided over 512 thr), zero out-acc ----
    for (int i = tid; i < BM * 10; i += 512) xls[i] = x[rowbase * 10 + i];
    if (tid < 128) oacc[tid] = 0.f;
    __syncthreads();

    // ---- layer 1: one K=32 MFMA pass; h -> LDS in fragment order ----
    {
        s16x8 afr[4];
#pragma unroll
        for (int m = 0; m < 4; ++m) {
            int r = m * 16 + l15;
            float v[8];
            if (g == 0) {                    // k=0..7 : oh * phi
                float phi = xls[r * 10 + 9];
#pragma unroll
                for (int j = 0; j < 8; ++j) v[j] = xls[r * 10 + j] * phi;
            } else if (g == 1) {             // k=8..15 : oh
#pragma unroll
                for (int j = 0; j < 8; ++j) v[j] = xls[r * 10 + j];
            } else if (g == 2) {             // k=16,17 : delta, 1
                v[0] = xls[r * 10 + 8]; v[1] = 1.f;
#pragma unroll
                for (int j = 2; j < 8; ++j) v[j] = 0.f;
            } else {                         // k=24..31 : 0
#pragma unroll
                for (int j = 0; j < 8; ++j) v[j] = 0.f;
            }
            s16x8 a;
#pragma unroll
            for (int j = 0; j < 8; ++j) a[j] = f2bf(v[j]);
            afr[m] = a;
        }
#pragma unroll
        for (int nf = 0; nf < 4; ++nf) {
            int col = wv * 64 + nf * 16 + l15;
            s16x8 bfr = *(const s16x8*)(waugS + col * 32 + g * 8);
            int chi = (col >> 3) * 512 + (col & 7);          // fragment-order column part
#pragma unroll
            for (int m = 0; m < 4; ++m) {
                f32x4 c = {0.f, 0.f, 0.f, 0.f};
                c = __builtin_amdgcn_mfma_f32_16x16x32_bf16(afr[m], bfr, c, 0, 0, 0);
#pragma unroll
                for (int r4 = 0; r4 < 4; ++r4) {
                    int row = m * 16 + g * 4 + r4;
                    float hv = c[r4];
                    hv = hv > 0.f ? hv : 0.f;
                    haug[chi + row * 8] = f2bf(hv);
                }
            }
        }
    }
    __syncthreads();   // h ready; haug read-only from here -> no more barriers

    // ---- layer 2: K=512 in 16 steps of 32; af via imm-offset ds_reads,
    //      bf ping-pong from L2, 2x-unrolled, barrier-free ----
    f32x4 acc[4][4];
#pragma unroll
    for (int m = 0; m < 4; ++m)
#pragma unroll
        for (int n = 0; n < 4; ++n) acc[m][n] = (f32x4){0.f, 0.f, 0.f, 0.f};

    const char* hb = (const char*)haug + g * 1024 + l15 * 16;  // af base
    const s16x8* __restrict__ w2v = (const s16x8*)w2s;
    const int colbase = wv * 64 + l15;

    s16x8 bfA[4], bfB[4];
#pragma unroll
    for (int n = 0; n < 4; ++n)
        bfA[n] = w2v[g * 512 + colbase + n * 16];              // t=0

    for (int tt = 0; tt < 8; ++tt) {
        // prefetch t = 2tt+1
        {
            const s16x8* p1 = w2v + ((2 * tt + 1) * 4 + g) * 512 + colbase;
#pragma unroll
            for (int n = 0; n < 4; ++n) bfB[n] = p1[n * 16];
        }
        {
            const char* hbt = hb + tt * 8192;
            s16x8 af[4];
#pragma unroll
            for (int m = 0; m < 4; ++m)
                af[m] = *(const s16x8*)(hbt + m * 256);
#pragma unroll
            for (int m = 0; m < 4; ++m)
#pragma unroll
                for (int n = 0; n < 4; ++n)
                    acc[m][n] = __builtin_amdgcn_mfma_f32_16x16x32_bf16(af[m], bfA[n], acc[m][n], 0, 0, 0);
        }
        // prefetch t = 2tt+2 (tt=7 reads 32KB past w2s = waugS region: in-bounds, unused)
        {
            const s16x8* p2 = w2v + ((2 * tt + 2) * 4 + g) * 512 + colbase;
#pragma unroll
            for (int n = 0; n < 4; ++n) bfA[n] = p2[n * 16];
        }
        {
            const char* hbt = hb + tt * 8192 + 4096;
            s16x8 af[4];
#pragma unroll
            for (int m = 0; m < 4; ++m)
                af[m] = *(const s16x8*)(hbt + m * 256);
#pragma unroll
            for (int m = 0; m < 4; ++m)
#pragma unroll
                for (int n = 0; n < 4; ++n)
                    acc[m][n] = __builtin_amdgcn_mfma_f32_16x16x32_bf16(af[m], bfB[n], acc[m][n], 0, 0, 0);
        }
    }

    // ---- layer 3: relu(acc+b2) @ w3, fused reduce ----
    float p[4][4][2];
#pragma unroll
    for (int m = 0; m < 4; ++m)
#pragma unroll
        for (int r4 = 0; r4 < 4; ++r4) { p[m][r4][0] = 0.f; p[m][r4][1] = 0.f; }

#pragma unroll
    for (int n = 0; n < 4; ++n) {
        int col = wv * 64 + n * 16 + l15;
        float bb2 = b2[col];
        float w30 = w3[col * 2 + 0];
        float w31 = w3[col * 2 + 1];
#pragma unroll
        for (int m = 0; m < 4; ++m)
#pragma unroll
            for (int r4 = 0; r4 < 4; ++r4) {
                float v = acc[m][n][r4] + bb2;
                v = v > 0.f ? v : 0.f;
                p[m][r4][0] += v * w30;
                p[m][r4][1] += v * w31;
            }
    }
    // butterfly-reduce over the 16 lanes sharing the same rows (same g)
#pragma unroll
    for (int m = 0; m < 4; ++m)
#pragma unroll
        for (int r4 = 0; r4 < 4; ++r4)
#pragma unroll
            for (int o = 0; o < 2; ++o) {
                float v = p[m][r4][o];
                v += __shfl_xor(v, 1);
                v += __shfl_xor(v, 2);
                v += __shfl_xor(v, 4);
                v += __shfl_xor(v, 8);
                if (l15 == 0) atomicAdd(&oacc[(m * 16 + g * 4 + r4) * 2 + o], v);
            }
    __syncthreads();

    if (tid < 128) {
        int row = tid >> 1, o = tid & 1;
        out[(rowbase + row) * 2 + o] = oacc[tid] + b3[o];
    }
}

extern "C" void kernel_launch(void* const* d_in, const int* in_sizes, int n_in,
                              void* d_out, int out_size, void* d_ws, size_t ws_size,
                              hipStream_t stream) {
    const float* x  = (const float*)d_in[0];
    const float* w1 = (const float*)d_in[1];
    const float* b1 = (const float*)d_in[2];
    const float* mw = (const float*)d_in[3];
    const float* mb = (const float*)d_in[4];
    const float* w2 = (const float*)d_in[5];
    const float* b2 = (const float*)d_in[6];
    const float* w3 = (const float*)d_in[7];
    const float* b3 = (const float*)d_in[8];
    float* out = (float*)d_out;

    short* w2s   = (short*)d_ws;          // 512 KB
    short* waugS = w2s + 512 * 512;       // 32 KB (also prefetch-overrun pad)

    prep_kernel<<<1024, 256, 0, stream>>>(w1, b1, mw, mb, w2, w2s, waugS);
    fused_mlp<<<65536 / BM, 512, 0, stream>>>(x, waugS, w2s, b2, w3, b3, out);
}

// Round 9
// 55.957 us; speedup vs baseline: 1.4676x; 1.2675x over previous
//
#include <hip/hip_runtime.h>

// Problem: N=65536 rows, H=512, E=8, OUT=2.
//   oh=x[:,0:8], delta=x[:,8], phi=x[:,9]
//   h  = relu(delta*w1 + b1 + phi*(oh@meta_w) + oh@meta_b)   -> one K=32 bf16 MFMA GEMM
//   h2 = relu(h @ w2 + b2)                                   -> main GEMM, bf16 MFMA, K=512
//   out = h2 @ w3 + b3                                       -> fused shuffle-reduce epilogue
//
// R9: register-budget engineering. Unified file = 512 regs/SIMD-slot; a 8-wave
// block co-residing 2/CU (4 waves/SIMD) needs <=128 unified regs/wave.
//   K-loop live: acc 64 (AGPR) + af 16 + bf 16 + addr ~12  = ~108  OK
//   epilogue:  p[32] replaced by per-(m,r4) immediate reduce (~16 live)
//   no bf ping-pong (TLP at 4 waves/SIMD hides L2 latency, not ILP)
// -> __launch_bounds__(512,4) now fits with margin, zero spill expected.

#define BM 64

typedef float f32x4 __attribute__((ext_vector_type(4)));
typedef short s16x8 __attribute__((ext_vector_type(8)));

__device__ __forceinline__ short f2bf(float f) {
    union { float f; unsigned u; } c; c.f = f;
    unsigned u = c.u;
    return (short)((u + 0x7FFFu + ((u >> 16) & 1u)) >> 16);  // RNE
}

// ---------------- prep: build bf16 weight images in workspace ----------------
// w2s layout: [ks=16][g=4][n=512][j=8] bf16  (B-fragment order)
//   element (ks,g,n,j) = w2[k][n] with k = ks*32 + g*8 + j
// waugS layout: [col=512][k=32] bf16, rows of W' = [meta_w(8); meta_b(8); w1; b1; 0...]
__global__ void prep_kernel(const float* __restrict__ w1, const float* __restrict__ b1,
                            const float* __restrict__ mw, const float* __restrict__ mb,
                            const float* __restrict__ w2,
                            short* __restrict__ w2s, short* __restrict__ waugS) {
    int id = blockIdx.x * 256 + threadIdx.x;
    if (id < 512 * 512) {
        int k = id / 512, n = id % 512;
        int ks = k >> 5, g = (k >> 3) & 3, j = k & 7;
        w2s[(((ks * 4 + g) * 512) + n) * 8 + j] = f2bf(w2[id]);
    }
    if (id < 512 * 32) {
        int col = id >> 5, k = id & 31;
        float v = 0.f;
        if (k < 8)        v = mw[k * 512 + col];
        else if (k < 16)  v = mb[(k - 8) * 512 + col];
        else if (k == 16) v = w1[col];
        else if (k == 17) v = b1[col];
        waugS[col * 32 + k] = f2bf(v);
    }
}

// ---------------- fused MLP ----------------
// grid 1024 blocks x 512 threads (8 waves). Block tile: 64 rows x 512 cols.
// Wave w owns cols [w*64, w*64+64), all 64 rows -> acc 4(m) x 4(n) frags.
__global__ __launch_bounds__(512, 4) void fused_mlp(
    const float* __restrict__ x, const short* __restrict__ waugS,
    const short* __restrict__ w2s, const float* __restrict__ b2,
    const float* __restrict__ w3, const float* __restrict__ b3,
    float* __restrict__ out) {

    // h in FRAGMENT order: short idx = (k>>3)*512 + row*8 + (k&7)
    __shared__ __align__(16) short haug[64 * 512];          // 64KB
    __shared__ float xls[64 * 10];                          // 2560 B
    __shared__ float oacc[128];                             // 512 B

    const int tid  = threadIdx.x;
    const int wv   = tid >> 6;           // 0..7
    const int lane = tid & 63;
    const int l15  = lane & 15;
    const int g    = lane >> 4;
    const long rowbase = (long)blockIdx.x * BM;

    // ---- load x tile (64x10 f32 = 640 floats, strided over 512 thr), zero out-acc ----
    for (int i = tid; i < BM * 10; i += 512) xls[i] = x[rowbase * 10 + i];
    if (tid < 128) oacc[tid] = 0.f;
    __syncthreads();

    // ---- layer 1: one K=32 MFMA pass; h -> LDS in fragment order ----
    {
        s16x8 afr[4];
#pragma unroll
        for (int m = 0; m < 4; ++m) {
            int r = m * 16 + l15;
            float v[8];
            if (g == 0) {                    // k=0..7 : oh * phi
                float phi = xls[r * 10 + 9];
#pragma unroll
                for (int j = 0; j < 8; ++j) v[j] = xls[r * 10 + j] * phi;
            } else if (g == 1) {             // k=8..15 : oh
#pragma unroll
                for (int j = 0; j < 8; ++j) v[j] = xls[r * 10 + j];
            } else if (g == 2) {             // k=16,17 : delta, 1
                v[0] = xls[r * 10 + 8]; v[1] = 1.f;
#pragma unroll
                for (int j = 2; j < 8; ++j) v[j] = 0.f;
            } else {                         // k=24..31 : 0
#pragma unroll
                for (int j = 0; j < 8; ++j) v[j] = 0.f;
            }
            s16x8 a;
#pragma unroll
            for (int j = 0; j < 8; ++j) a[j] = f2bf(v[j]);
            afr[m] = a;
        }
#pragma unroll
        for (int nf = 0; nf < 4; ++nf) {
            int col = wv * 64 + nf * 16 + l15;
            s16x8 bfr = *(const s16x8*)(waugS + col * 32 + g * 8);
            int chi = (col >> 3) * 512 + (col & 7);          // fragment-order column part
#pragma unroll
            for (int m = 0; m < 4; ++m) {
                f32x4 c = {0.f, 0.f, 0.f, 0.f};
                c = __builtin_amdgcn_mfma_f32_16x16x32_bf16(afr[m], bfr, c, 0, 0, 0);
#pragma unroll
                for (int r4 = 0; r4 < 4; ++r4) {
                    int row = m * 16 + g * 4 + r4;
                    float hv = c[r4];
                    hv = hv > 0.f ? hv : 0.f;
                    haug[chi + row * 8] = f2bf(hv);
                }
            }
        }
    }
    __syncthreads();   // h ready; haug read-only from here -> no more barriers

    // ---- layer 2: K=512 in 16 steps of 32; af via imm-offset ds_reads,
    //      bf straight from L2 each step (TLP hides latency), barrier-free ----
    f32x4 acc[4][4];
#pragma unroll
    for (int m = 0; m < 4; ++m)
#pragma unroll
        for (int n = 0; n < 4; ++n) acc[m][n] = (f32x4){0.f, 0.f, 0.f, 0.f};

    const char* hb = (const char*)haug + g * 1024 + l15 * 16;  // af base
    const s16x8* __restrict__ w2v = (const s16x8*)w2s;
    const int colbase = wv * 64 + l15;

    for (int t = 0; t < 16; ++t) {
        const s16x8* p = w2v + (t * 4 + g) * 512 + colbase;
        s16x8 bf[4];
#pragma unroll
        for (int n = 0; n < 4; ++n) bf[n] = p[n * 16];
        const char* hbt = hb + t * 4096;
        s16x8 af[4];
#pragma unroll
        for (int m = 0; m < 4; ++m)
            af[m] = *(const s16x8*)(hbt + m * 256);
#pragma unroll
        for (int m = 0; m < 4; ++m)
#pragma unroll
            for (int n = 0; n < 4; ++n)
                acc[m][n] = __builtin_amdgcn_mfma_f32_16x16x32_bf16(af[m], bf[n], acc[m][n], 0, 0, 0);
    }

    // ---- layer 3: relu(acc+b2) @ w3, per-(m,r4) immediate reduce (low reg pressure) ----
    float bb2[4], w30[4], w31[4];
#pragma unroll
    for (int n = 0; n < 4; ++n) {
        int col = wv * 64 + n * 16 + l15;
        bb2[n] = b2[col];
        w30[n] = w3[col * 2 + 0];
        w31[n] = w3[col * 2 + 1];
    }
#pragma unroll
    for (int m = 0; m < 4; ++m) {
#pragma unroll
        for (int r4 = 0; r4 < 4; ++r4) {
            float s0 = 0.f, s1 = 0.f;
#pragma unroll
            for (int n = 0; n < 4; ++n) {
                float v = acc[m][n][r4] + bb2[n];
                v = v > 0.f ? v : 0.f;
                s0 += v * w30[n];
                s1 += v * w31[n];
            }
            s0 += __shfl_xor(s0, 1); s1 += __shfl_xor(s1, 1);
            s0 += __shfl_xor(s0, 2); s1 += __shfl_xor(s1, 2);
            s0 += __shfl_xor(s0, 4); s1 += __shfl_xor(s1, 4);
            s0 += __shfl_xor(s0, 8); s1 += __shfl_xor(s1, 8);
            if (l15 == 0) {
                int row = m * 16 + g * 4 + r4;
                atomicAdd(&oacc[row * 2 + 0], s0);
                atomicAdd(&oacc[row * 2 + 1], s1);
            }
        }
    }
    __syncthreads();

    if (tid < 128) {
        int row = tid >> 1, o = tid & 1;
        out[(rowbase + row) * 2 + o] = oacc[tid] + b3[o];
    }
}

extern "C" void kernel_launch(void* const* d_in, const int* in_sizes, int n_in,
                              void* d_out, int out_size, void* d_ws, size_t ws_size,
                              hipStream_t stream) {
    const float* x  = (const float*)d_in[0];
    const float* w1 = (const float*)d_in[1];
    const float* b1 = (const float*)d_in[2];
    const float* mw = (const float*)d_in[3];
    const float* mb = (const float*)d_in[4];
    const float* w2 = (const float*)d_in[5];
    const float* b2 = (const float*)d_in[6];
    const float* w3 = (const float*)d_in[7];
    const float* b3 = (const float*)d_in[8];
    float* out = (float*)d_out;

    short* w2s   = (short*)d_ws;          // 512 KB
    short* waugS = w2s + 512 * 512;       // 32 KB

    prep_kernel<<<1024, 256, 0, stream>>>(w1, b1, mw, mb, w2, w2s, waugS);
    fused_mlp<<<65536 / BM, 512, 0, stream>>>(x, waugS, w2s, b2, w3, b3, out);
}